// Round 11
// baseline (231.126 us; speedup 1.0000x reference)
//
#include <hip/hip_runtime.h>
#include <cstdint>

#define BB 2
#define NN 16384
#define MM 4096
#define CF 256
#define CT 128
#define CP 64
#define NPB 64      // query points per block (grid 512 -> staging FETCH low)
#define CHUNK 2048  // ref points staged in LDS per pass (32 KB)
#define TPB 512     // proven best shape

// All-FP32 monolithic kernel. Round-10 lean per-pair network (bit-exact
// pre-doubled refs + min/med3 value net) combined with R8's LDS-read
// amortization: 16 sub-lanes per lane-group, each lane owns TWO points as
// explicit scalars, so one ds_read_b128 serves 2 (point,ref) pairs ->
// LDS pipe demand halves (theory: it was ~80% busy, gating VALU at ~45%).
// Phase 2 byte-identical to round 10.
__global__ __launch_bounds__(TPB, 4) void fp_fused_kernel(
    const float* __restrict__ coords,      // [B,N,3]
    const float* __restrict__ ref_coords,  // [B,M,3]
    const float* __restrict__ refF,        // [B,256,M]
    const float* __restrict__ refT,        // [B,128,M]
    const float* __restrict__ pf,          // [B,64,N]
    float* __restrict__ out)               // [B,320,N] ++ [B,128,N]
{
#pragma clang fp contract(off)
    __shared__ float4 refs[CHUNK];      // 32 KB (2x, 2y, 2z, rr)
    __shared__ int    s_idx[NPB * 3];
    __shared__ float  s_w[NPB * 3];

    const int tid = threadIdx.x;
    const int b   = blockIdx.y;
    const int n0  = blockIdx.x * NPB;

    // ------------- phase 1: 3-NN, 16 lanes per PAIR of query points ---------
    const int pl = tid >> 4;            // lane-group 0..31 (owns points 2pl, 2pl+1)
    const int s  = tid & 15;            // sub-lane 0..15

    const float* cp = coords + ((size_t)b * NN + n0 + 2 * pl) * 3;
    const float cxA = cp[0], cyA = cp[1], czA = cp[2];
    const float cxB = cp[3], cyB = cp[4], czB = cp[5];
    const float ccA = (cxA * cxA + cyA * cyA) + czA * czA;  // numpy sum order
    const float ccB = (cxB * cxB + cyB * cyB) + czB * czB;

    float dA0 = INFINITY, dA1 = INFINITY, dA2 = INFINITY;
    float dB0 = INFINITY, dB1 = INFINITY, dB2 = INFINITY;
    int   iA0 = 0, iA1 = 0, iA2 = 0;
    int   iB0 = 0, iB1 = 0, iB2 = 0;

    const float* rc = ref_coords + (size_t)b * MM * 3;

    for (int ch = 0; ch < MM / CHUNK; ++ch) {
        __syncthreads();                 // refs[] reuse guard
        for (int e = tid; e < CHUNK; e += TPB) {
            const int j = ch * CHUNK + e;
            const float x = rc[3 * j + 0];
            const float y = rc[3 * j + 1];
            const float z = rc[3 * j + 2];
            // rr in numpy order; xyz pre-doubled (exact exponent shift):
            // fl(c*(2r)) = 2*fl(c*r), fl(2a+2b) = 2*fl(a+b) -> dd bit-exact.
            refs[e] = make_float4(x + x, y + y, z + z, (x * x + y * y) + z * z);
        }
        __syncthreads();

        // lane scans e = s, s+16, ... ascending -> strict '<' keeps lowest idx
        #pragma unroll 4
        for (int it = 0; it < CHUNK / 16; ++it) {
            const int e = s + (it << 4);
            const float4 r = refs[e];
            const int j = ch * CHUNK + e;

            // ---- point A ----
            {
                const float dot2 = (cxA * r.x + cyA * r.y) + czA * r.z;
                const float dd   = (ccA + r.w) - dot2;       // == numpy d2
                const bool l2 = dd < dA2;
                const bool l1 = dd < dA1;
                const bool l0 = dd < dA0;
                iA2 = l2 ? (l1 ? iA1 : j) : iA2;
                iA1 = l1 ? (l0 ? iA0 : j) : iA1;
                iA0 = l0 ? j : iA0;
                const float v2 = __builtin_amdgcn_fmed3f(dd, dA1, dA2);
                const float v1 = __builtin_amdgcn_fmed3f(dd, dA0, dA1);
                const float v0 = fminf(dd, dA0);
                dA2 = v2; dA1 = v1; dA0 = v0;
            }
            // ---- point B ----
            {
                const float dot2 = (cxB * r.x + cyB * r.y) + czB * r.z;
                const float dd   = (ccB + r.w) - dot2;
                const bool l2 = dd < dB2;
                const bool l1 = dd < dB1;
                const bool l0 = dd < dB0;
                iB2 = l2 ? (l1 ? iB1 : j) : iB2;
                iB1 = l1 ? (l0 ? iB0 : j) : iB1;
                iB0 = l0 ? j : iB0;
                const float v2 = __builtin_amdgcn_fmed3f(dd, dB1, dB2);
                const float v1 = __builtin_amdgcn_fmed3f(dd, dB0, dB1);
                const float v0 = fminf(dd, dB0);
                dB2 = v2; dB1 = v1; dB0 = v0;
            }
        }
    }

    // lexicographic (d, idx) insert: lower index wins exact ties (stable top_k)
    auto insA = [&](float e, int f) {
        const bool l2 = (e < dA2) || (e == dA2 && f < iA2);
        const bool l1 = (e < dA1) || (e == dA1 && f < iA1);
        const bool l0 = (e < dA0) || (e == dA0 && f < iA0);
        dA2 = l2 ? (l1 ? dA1 : e) : dA2;  iA2 = l2 ? (l1 ? iA1 : f) : iA2;
        dA1 = l1 ? (l0 ? dA0 : e) : dA1;  iA1 = l1 ? (l0 ? iA0 : f) : iA1;
        dA0 = l0 ? e : dA0;               iA0 = l0 ? f : iA0;
    };
    auto insB = [&](float e, int f) {
        const bool l2 = (e < dB2) || (e == dB2 && f < iB2);
        const bool l1 = (e < dB1) || (e == dB1 && f < iB1);
        const bool l0 = (e < dB0) || (e == dB0 && f < iB0);
        dB2 = l2 ? (l1 ? dB1 : e) : dB2;  iB2 = l2 ? (l1 ? iB1 : f) : iB2;
        dB1 = l1 ? (l0 ? dB0 : e) : dB1;  iB1 = l1 ? (l0 ? iB0 : f) : iB1;
        dB0 = l0 ? e : dB0;               iB0 = l0 ? f : iB0;
    };

    // butterfly across the 16 sub-lanes (xor<16 stays in-group, in-wave)
    for (int off = 1; off < 16; off <<= 1) {
        {
            const float e0 = __shfl_xor(dA0, off, 64);
            const float e1 = __shfl_xor(dA1, off, 64);
            const float e2 = __shfl_xor(dA2, off, 64);
            const int   f0 = __shfl_xor(iA0, off, 64);
            const int   f1 = __shfl_xor(iA1, off, 64);
            const int   f2 = __shfl_xor(iA2, off, 64);
            insA(e0, f0); insA(e1, f1); insA(e2, f2);
        }
        {
            const float e0 = __shfl_xor(dB0, off, 64);
            const float e1 = __shfl_xor(dB1, off, 64);
            const float e2 = __shfl_xor(dB2, off, 64);
            const int   f0 = __shfl_xor(iB0, off, 64);
            const int   f1 = __shfl_xor(iB1, off, 64);
            const int   f2 = __shfl_xor(iB2, off, 64);
            insB(e0, f0); insB(e1, f1); insB(e2, f2);
        }
    }

    if (s == 0) {
        const int pA = 2 * pl, pB = 2 * pl + 1;
        {
            float w0 = 1.0f / (dA0 + 1e-8f);     // IEEE divs, numpy order
            float w1 = 1.0f / (dA1 + 1e-8f);
            float w2 = 1.0f / (dA2 + 1e-8f);
            const float sum = (w0 + w1) + w2;
            s_idx[pA * 3 + 0] = iA0;
            s_idx[pA * 3 + 1] = iA1;
            s_idx[pA * 3 + 2] = iA2;
            s_w[pA * 3 + 0] = w0 / sum;
            s_w[pA * 3 + 1] = w1 / sum;
            s_w[pA * 3 + 2] = w2 / sum;
        }
        {
            float w0 = 1.0f / (dB0 + 1e-8f);
            float w1 = 1.0f / (dB1 + 1e-8f);
            float w2 = 1.0f / (dB2 + 1e-8f);
            const float sum = (w0 + w1) + w2;
            s_idx[pB * 3 + 0] = iB0;
            s_idx[pB * 3 + 1] = iB1;
            s_idx[pB * 3 + 2] = iB2;
            s_w[pB * 3 + 0] = w0 / sum;
            s_w[pB * 3 + 1] = w1 / sum;
            s_w[pB * 3 + 2] = w2 / sum;
        }
    }
    __syncthreads();

    // ---------------- phase 2: interpolate + concat (== round 10) -----------
    const int g  = tid >> 5;
    const int l  = tid & 31;
    const int p0 = 2 * l;

    auto clampi = [](int v) { return v < 0 ? 0 : (v > MM - 1 ? MM - 1 : v); };
    const int   ia0 = clampi(s_idx[p0 * 3 + 0]);
    const int   ia1 = clampi(s_idx[p0 * 3 + 1]);
    const int   ia2 = clampi(s_idx[p0 * 3 + 2]);
    const int   ib0 = clampi(s_idx[p0 * 3 + 3]);
    const int   ib1 = clampi(s_idx[p0 * 3 + 4]);
    const int   ib2 = clampi(s_idx[p0 * 3 + 5]);
    const float wa0 = s_w[p0 * 3 + 0], wa1 = s_w[p0 * 3 + 1], wa2 = s_w[p0 * 3 + 2];
    const float wb0 = s_w[p0 * 3 + 3], wb1 = s_w[p0 * 3 + 4], wb2 = s_w[p0 * 3 + 5];

    const size_t outT_base = (size_t)BB * (CF + CP) * NN;

    for (int it = 0; it < (CF + CP + CT) / 16; ++it) {
        const int row = it * 16 + g;
        if (row < CF) {
            const float* src = refF + ((size_t)b * CF + row) * MM;
            float* dst = out + ((size_t)b * (CF + CP) + row) * NN + n0;
            float2 pr;
            pr.x = (wa0 * src[ia0] + wa1 * src[ia1]) + wa2 * src[ia2];
            pr.y = (wb0 * src[ib0] + wb1 * src[ib1]) + wb2 * src[ib2];
            *reinterpret_cast<float2*>(dst + p0) = pr;
        } else if (row < CF + CP) {
            const float* src = pf + ((size_t)b * CP + (row - CF)) * NN + n0;
            float* dst = out + ((size_t)b * (CF + CP) + row) * NN + n0;
            *reinterpret_cast<float2*>(dst + p0) =
                *reinterpret_cast<const float2*>(src + p0);
        } else {
            const int tr = row - (CF + CP);
            const float* src = refT + ((size_t)b * CT + tr) * MM;
            float* dst = out + outT_base + ((size_t)b * CT + tr) * NN + n0;
            float2 pr;
            pr.x = (wa0 * src[ia0] + wa1 * src[ia1]) + wa2 * src[ia2];
            pr.y = (wb0 * src[ib0] + wb1 * src[ib1]) + wb2 * src[ib2];
            *reinterpret_cast<float2*>(dst + p0) = pr;
        }
    }
}

extern "C" void kernel_launch(void* const* d_in, const int* in_sizes, int n_in,
                              void* d_out, int out_size, void* d_ws, size_t ws_size,
                              hipStream_t stream) {
    const float* coords     = (const float*)d_in[0];
    const float* ref_coords = (const float*)d_in[1];
    const float* refF       = (const float*)d_in[2];
    const float* refT       = (const float*)d_in[3];
    const float* pf         = (const float*)d_in[4];
    float* out = (float*)d_out;

    hipLaunchKernelGGL(fp_fused_kernel, dim3(NN / NPB, BB), dim3(TPB), 0, stream,
                       coords, ref_coords, refF, refT, pf, out);
}

// Round 12
// 217.330 us; speedup vs baseline: 1.0635x; 1.0635x over previous
//
#include <hip/hip_runtime.h>
#include <cstdint>

#define BB 2
#define NN 16384
#define MM 4096
#define CF 256
#define CT 128
#define CP 64
#define NPB 64      // query points per block (grid 512 -> staging FETCH low)
#define CHUNK 2048  // ref points staged in LDS per pass (32 KB)
#define TPB 512     // proven best shape (R10: 154 us)

// All-FP32 monolithic kernel — R10 base (bit-exact pre-doubled refs) with the
// insertion network wrapped in a per-lane branch:
//   always: dot2(5) + dd(2) + 1 cmp          = 8 VALU ops
//   taken (~65% of wave-iters): +2 cmp +4 cndmask +med3 +min +cndmask ≈ 9
// The wave skips the insert body entirely (s_cbranch_execz) when no lane
// inserts (~35% of wave-iterations, rising as the scan progresses).
// Tie semantics preserved exactly:
//   dd == d2v -> branch not taken = incumbent (lower index) kept  (correct)
//   inside: l2 is known true; d2v = l1?d1:dd, d1 = med3(dd,d0,d1) (exact
//   selection: dd<d0->d0, d0<=dd<d1->dd, dd>=d1->d1), d0 = min(dd,d0);
//   index net keeps strict-< so first-seen (lowest j) wins ties.
// Phase 2 byte-identical to R10.
__global__ __launch_bounds__(TPB, 4) void fp_fused_kernel(
    const float* __restrict__ coords,      // [B,N,3]
    const float* __restrict__ ref_coords,  // [B,M,3]
    const float* __restrict__ refF,        // [B,256,M]
    const float* __restrict__ refT,        // [B,128,M]
    const float* __restrict__ pf,          // [B,64,N]
    float* __restrict__ out)               // [B,320,N] ++ [B,128,N]
{
#pragma clang fp contract(off)
    __shared__ float4 refs[CHUNK];      // 32 KB (2x, 2y, 2z, rr)
    __shared__ int    s_idx[NPB * 3];
    __shared__ float  s_w[NPB * 3];

    const int tid = threadIdx.x;
    const int b   = blockIdx.y;
    const int n0  = blockIdx.x * NPB;

    // ---------------- phase 1: 3-NN, 8 lanes per query point ----------------
    const int pl = tid >> 3;            // point-in-block 0..63
    const int s  = tid & 7;             // sub-lane 0..7
    const int n  = n0 + pl;

    const float* cp = coords + ((size_t)b * NN + n) * 3;
    const float cx = cp[0];
    const float cy = cp[1];
    const float cz = cp[2];
    const float cc = (cx * cx + cy * cy) + cz * cz;   // numpy sum order

    float d0 = INFINITY, d1 = INFINITY, d2v = INFINITY;
    int   i0 = 0, i1 = 0, i2 = 0;       // benign fallbacks (no sentinels)

    const float* rc = ref_coords + (size_t)b * MM * 3;

    for (int ch = 0; ch < MM / CHUNK; ++ch) {
        __syncthreads();                 // refs[] reuse guard
        for (int e = tid; e < CHUNK; e += TPB) {
            const int j = ch * CHUNK + e;
            const float x = rc[3 * j + 0];
            const float y = rc[3 * j + 1];
            const float z = rc[3 * j + 2];
            // rr in numpy order; xyz pre-doubled (exact exponent shift):
            // fl(c*(2r)) = 2*fl(c*r), fl(2a+2b) = 2*fl(a+b) -> dd bit-exact.
            refs[e] = make_float4(x + x, y + y, z + z, (x * x + y * y) + z * z);
        }
        __syncthreads();

        // lane scans e = s, s+8, ... ascending -> strict '<' keeps lowest idx
        #pragma unroll 4
        for (int it = 0; it < CHUNK / 8; ++it) {
            const int e = s + (it << 3);
            const float4 r = refs[e];
            const float dot2 = (cx * r.x + cy * r.y) + cz * r.z;
            const float dd   = (cc + r.w) - dot2;        // == numpy d2
            if (dd < d2v) {                              // rare late in scan
                const int j = ch * CHUNK + e;
                const bool l1 = dd < d1;
                const bool l0 = dd < d0;
                i2 = l1 ? i1 : j;
                i1 = l1 ? (l0 ? i0 : j) : i1;
                i0 = l0 ? j : i0;
                d2v = l1 ? d1 : dd;
                d1  = __builtin_amdgcn_fmed3f(dd, d0, d1);
                d0  = fminf(dd, d0);
            }
        }
    }

    // lexicographic (d, idx) insert: lower index wins exact ties (stable top_k)
    auto ins = [&](float e, int f) {
        const bool l2 = (e < d2v) || (e == d2v && f < i2);
        const bool l1 = (e < d1)  || (e == d1  && f < i1);
        const bool l0 = (e < d0)  || (e == d0  && f < i0);
        d2v = l2 ? (l1 ? d1 : e) : d2v;  i2 = l2 ? (l1 ? i1 : f) : i2;
        d1  = l1 ? (l0 ? d0 : e) : d1;   i1 = l1 ? (l0 ? i0 : f) : i1;
        d0  = l0 ? e : d0;               i0 = l0 ? f : i0;
    };

    // butterfly across the 8 sub-lanes (xor<8 stays in-group, in-wave)
    for (int off = 1; off < 8; off <<= 1) {
        const float e0 = __shfl_xor(d0,  off, 64);
        const float e1 = __shfl_xor(d1,  off, 64);
        const float e2 = __shfl_xor(d2v, off, 64);
        const int   f0 = __shfl_xor(i0,  off, 64);
        const int   f1 = __shfl_xor(i1,  off, 64);
        const int   f2 = __shfl_xor(i2,  off, 64);
        ins(e0, f0);
        ins(e1, f1);
        ins(e2, f2);
    }

    if (s == 0) {
        float w0 = 1.0f / (d0  + 1e-8f);     // IEEE divs, numpy order
        float w1 = 1.0f / (d1  + 1e-8f);
        float w2 = 1.0f / (d2v + 1e-8f);
        const float sum = (w0 + w1) + w2;
        s_idx[pl * 3 + 0] = i0;
        s_idx[pl * 3 + 1] = i1;
        s_idx[pl * 3 + 2] = i2;
        s_w[pl * 3 + 0] = w0 / sum;
        s_w[pl * 3 + 1] = w1 / sum;
        s_w[pl * 3 + 2] = w2 / sum;
    }
    __syncthreads();

    // ---------------- phase 2: interpolate + concat (== R10) ----------------
    const int g  = tid >> 5;
    const int l  = tid & 31;
    const int p0 = 2 * l;

    auto clampi = [](int v) { return v < 0 ? 0 : (v > MM - 1 ? MM - 1 : v); };
    const int   ia0 = clampi(s_idx[p0 * 3 + 0]);
    const int   ia1 = clampi(s_idx[p0 * 3 + 1]);
    const int   ia2 = clampi(s_idx[p0 * 3 + 2]);
    const int   ib0 = clampi(s_idx[p0 * 3 + 3]);
    const int   ib1 = clampi(s_idx[p0 * 3 + 4]);
    const int   ib2 = clampi(s_idx[p0 * 3 + 5]);
    const float wa0 = s_w[p0 * 3 + 0], wa1 = s_w[p0 * 3 + 1], wa2 = s_w[p0 * 3 + 2];
    const float wb0 = s_w[p0 * 3 + 3], wb1 = s_w[p0 * 3 + 4], wb2 = s_w[p0 * 3 + 5];

    const size_t outT_base = (size_t)BB * (CF + CP) * NN;

    for (int it = 0; it < (CF + CP + CT) / 16; ++it) {
        const int row = it * 16 + g;
        if (row < CF) {
            const float* src = refF + ((size_t)b * CF + row) * MM;
            float* dst = out + ((size_t)b * (CF + CP) + row) * NN + n0;
            float2 pr;
            pr.x = (wa0 * src[ia0] + wa1 * src[ia1]) + wa2 * src[ia2];
            pr.y = (wb0 * src[ib0] + wb1 * src[ib1]) + wb2 * src[ib2];
            *reinterpret_cast<float2*>(dst + p0) = pr;
        } else if (row < CF + CP) {
            const float* src = pf + ((size_t)b * CP + (row - CF)) * NN + n0;
            float* dst = out + ((size_t)b * (CF + CP) + row) * NN + n0;
            *reinterpret_cast<float2*>(dst + p0) =
                *reinterpret_cast<const float2*>(src + p0);
        } else {
            const int tr = row - (CF + CP);
            const float* src = refT + ((size_t)b * CT + tr) * MM;
            float* dst = out + outT_base + ((size_t)b * CT + tr) * NN + n0;
            float2 pr;
            pr.x = (wa0 * src[ia0] + wa1 * src[ia1]) + wa2 * src[ia2];
            pr.y = (wb0 * src[ib0] + wb1 * src[ib1]) + wb2 * src[ib2];
            *reinterpret_cast<float2*>(dst + p0) = pr;
        }
    }
}

extern "C" void kernel_launch(void* const* d_in, const int* in_sizes, int n_in,
                              void* d_out, int out_size, void* d_ws, size_t ws_size,
                              hipStream_t stream) {
    const float* coords     = (const float*)d_in[0];
    const float* ref_coords = (const float*)d_in[1];
    const float* refF       = (const float*)d_in[2];
    const float* refT       = (const float*)d_in[3];
    const float* pf         = (const float*)d_in[4];
    float* out = (float*)d_out;

    hipLaunchKernelGGL(fp_fused_kernel, dim3(NN / NPB, BB), dim3(TPB), 0, stream,
                       coords, ref_coords, refF, refT, pf, out);
}